// Round 1
// baseline (597.492 us; speedup 1.0000x reference)
//
#include <hip/hip_runtime.h>

#define HW 2304
#define W48 48

// ---------------------------------------------------------------------------
// prep: build rec_ext (float4: c0,c1,c2,walls) for all 16 timesteps,
//       build cur0 (frame 0 + walls), copy frame 0 (3ch) to d_out.
// ---------------------------------------------------------------------------
__global__ __launch_bounds__(256) void prep_kernel(
    const float* __restrict__ x, const float* __restrict__ rec,
    const float* __restrict__ walls,
    float4* __restrict__ rec4, float4* __restrict__ cur0,
    float* __restrict__ dout)
{
    int id = blockIdx.x * 256 + threadIdx.x;
    if (id < 16 * HW) {
        int t = id / HW, p = id % HW;
        rec4[id] = make_float4(rec[(t * 3 + 0) * HW + p],
                               rec[(t * 3 + 1) * HW + p],
                               rec[(t * 3 + 2) * HW + p],
                               walls[p]);
    }
    if (id < HW) {
        cur0[id] = make_float4(x[0 * HW + id], x[1 * HW + id], x[2 * HW + id],
                               walls[id]);
    }
    if (id < 3 * HW) {
        dout[id] = x[id];  // frame 0, channels 0..2
    }
}

// ---------------------------------------------------------------------------
// dist: block = (t-group, sy). For each (t, sx) pair: F = per-pixel 4ch sq-diff
// between cur and rec[t] shifted by (sy,sx); 5x5 circular box-sum via separable
// row/col sums; packed (dist_bits<<32 | m) min into per-thread registers.
// ---------------------------------------------------------------------------
__global__ __launch_bounds__(256) void dist_kernel(
    const float4* __restrict__ rec4, const float4* __restrict__ cur4,
    unsigned long long* __restrict__ partials, int tpb)
{
    __shared__ float4 recS[HW];   // 36 KiB
    __shared__ float  Fs[HW];     // 9 KiB
    __shared__ float  Rs[HW];     // 9 KiB

    const int tid = threadIdx.x;
    const int b   = blockIdx.x;
    const int sy  = b % W48;
    const int tg  = b / W48;

    float4 curR[9];
    unsigned long long best[9];
    int pyk[9], pxk[9], ryk[9];
#pragma unroll
    for (int k = 0; k < 9; k++) {
        int p   = tid + 256 * k;
        curR[k] = cur4[p];
        best[k] = ~0ULL;
        pyk[k]  = p / W48;
        pxk[k]  = p % W48;
        int ry  = pyk[k] + sy; if (ry >= W48) ry -= W48;
        ryk[k]  = ry;
    }

    for (int tt = 0; tt < tpb; tt++) {
        const int t = tg * tpb + tt;
        __syncthreads();
#pragma unroll
        for (int k = 0; k < 9; k++) {
            int p = tid + 256 * k;
            recS[p] = rec4[t * HW + p];
        }
        __syncthreads();

        for (int sx = 0; sx < W48; sx++) {
            // phase A: F(u) = sum_c (cur - rec_shifted)^2
#pragma unroll
            for (int k = 0; k < 9; k++) {
                int rx = pxk[k] + sx; if (rx >= W48) rx -= W48;
                float4 r = recS[ryk[k] * W48 + rx];
                float d0 = curR[k].x - r.x;
                float d1 = curR[k].y - r.y;
                float d2 = curR[k].z - r.z;
                float d3 = curR[k].w - r.w;
                Fs[tid + 256 * k] = d0 * d0 + d1 * d1 + d2 * d2 + d3 * d3;
            }
            __syncthreads();
            // phase B: row box sums (dx in [-2,2], circular)
#pragma unroll
            for (int k = 0; k < 9; k++) {
                int base = pyk[k] * W48;
                float s = 0.f;
#pragma unroll
                for (int dx = -2; dx <= 2; dx++) {
                    int cx = pxk[k] + dx;
                    if (cx < 0) cx += W48;
                    if (cx >= W48) cx -= W48;
                    s += Fs[base + cx];
                }
                Rs[tid + 256 * k] = s;
            }
            __syncthreads();
            // phase C: col box sums + packed-min update
#pragma unroll
            for (int k = 0; k < 9; k++) {
                float s = 0.f;
#pragma unroll
                for (int dy = -2; dy <= 2; dy++) {
                    int cy = pyk[k] + dy;
                    if (cy < 0) cy += W48;
                    if (cy >= W48) cy -= W48;
                    s += Rs[cy * W48 + pxk[k]];
                }
                int rx = pxk[k] + sx; if (rx >= W48) rx -= W48;
                unsigned int m =
                    (unsigned int)(t * HW + ryk[k] * W48 + rx);
                unsigned long long pk =
                    ((unsigned long long)__float_as_uint(s) << 32) | m;
                best[k] = pk < best[k] ? pk : best[k];
            }
            // no barrier needed here: next phase-A writes Fs (last read in B,
            // already barrier-separated); Rs next written after next barrier.
        }
    }
#pragma unroll
    for (int k = 0; k < 9; k++) {
        partials[(size_t)b * HW + tid + 256 * k] = best[k];
    }
}

// ---------------------------------------------------------------------------
// reduce_gather: per-position min over block partials; gather center pixel of
// the (t+1) patch; write output frame + next carry + per-element sq-error.
// ---------------------------------------------------------------------------
__global__ __launch_bounds__(256) void reduce_gather(
    const unsigned long long* __restrict__ partials, int nparts,
    const float4* __restrict__ rec4, const float* __restrict__ x,
    const float* __restrict__ walls,
    float4* __restrict__ curnext, float* __restrict__ dout,
    float* __restrict__ err, int step)
{
    int p = blockIdx.x * 256 + threadIdx.x;
    if (p >= HW) return;
    unsigned long long bestv = ~0ULL;
    for (int j = 0; j < nparts; j++) {
        unsigned long long v = partials[(size_t)j * HW + p];
        bestv = v < bestv ? v : bestv;
    }
    unsigned int m = (unsigned int)bestv;
    int t = m / HW, q = m % HW;
    float4 v = rec4[(t + 1) * HW + q];
    curnext[p] = v;
    dout[(step + 1) * 3 * HW + 0 * HW + p] = v.x;
    dout[(step + 1) * 3 * HW + 1 * HW + p] = v.y;
    dout[(step + 1) * 3 * HW + 2 * HW + p] = v.z;
    float t0 = x[((step + 1) * 3 + 0) * HW + p];
    float t1 = x[((step + 1) * 3 + 1) * HW + p];
    float t2 = x[((step + 1) * 3 + 2) * HW + p];
    float t3 = walls[p];
    float e = (v.x - t0) * (v.x - t0) + (v.y - t1) * (v.y - t1) +
              (v.z - t2) * (v.z - t2) + (v.w - t3) * (v.w - t3);
    err[step * HW + p] = e;
}

// ---------------------------------------------------------------------------
// loss: deterministic reduction of 2*HW squared errors -> mean of step means.
// loss = (sum0/9216 + sum1/9216)/2 = total/18432
// ---------------------------------------------------------------------------
__global__ __launch_bounds__(256) void loss_kernel(
    const float* __restrict__ err, float* __restrict__ dout)
{
    __shared__ float ssum[256];
    float s = 0.f;
    for (int i = threadIdx.x; i < 2 * HW; i += 256) s += err[i];
    ssum[threadIdx.x] = s;
    __syncthreads();
    for (int w = 128; w > 0; w >>= 1) {
        if (threadIdx.x < w) ssum[threadIdx.x] += ssum[threadIdx.x + w];
        __syncthreads();
    }
    if (threadIdx.x == 0) dout[9 * HW] = ssum[0] / 18432.0f;
}

extern "C" void kernel_launch(void* const* d_in, const int* in_sizes, int n_in,
                              void* d_out, int out_size, void* d_ws,
                              size_t ws_size, hipStream_t stream)
{
    const float* x     = (const float*)d_in[0];
    const float* rec   = (const float*)d_in[1];
    const float* walls = (const float*)d_in[2];
    float* dout = (float*)d_out;

    char* ws = (char*)d_ws;
    float4* rec4 = (float4*)ws;                                  // 589824 B
    float4* curb = (float4*)(ws + 589824);                       // 110592 B
    float*  err  = (float*)(ws + 589824 + 110592);               //  18432 B
    unsigned long long* partials =
        (unsigned long long*)(ws + 589824 + 110592 + 18432);

    size_t base = 589824 + 110592 + 18432;
    int tpb;
    if (ws_size >= base + (size_t)720 * HW * 8)      tpb = 1;   // 13.3 MB
    else if (ws_size >= base + (size_t)240 * HW * 8) tpb = 3;   //  4.4 MB
    else                                             tpb = 15;  //  0.9 MB
    int nblocks = W48 * (15 / tpb);

    prep_kernel<<<144, 256, 0, stream>>>(x, rec, walls, rec4, curb, dout);
    for (int step = 0; step < 2; step++) {
        dist_kernel<<<nblocks, 256, 0, stream>>>(rec4, curb + step * HW,
                                                 partials, tpb);
        reduce_gather<<<9, 256, 0, stream>>>(partials, nblocks, rec4, x, walls,
                                             curb + (step + 1) * HW, dout, err,
                                             step);
    }
    loss_kernel<<<1, 256, 0, stream>>>(err, dout);
}

// Round 2
// 302.382 us; speedup vs baseline: 1.9760x; 1.9760x over previous
//
#include <hip/hip_runtime.h>

#define HW 2304
#define W48 48
#define PAD_REC 49   // float4 per recS row (pad breaks 64B-stride bank alias)
#define FS_STRIDE 56 // floats per FsP row (48 + 4 halo, padded to mult of 8)
#define RS_STRIDE 52 // floats per Rs row (16B-aligned rows, +20-bank row shift)

// ---------------------------------------------------------------------------
// prep: build rec_ext (float4: c0,c1,c2,walls) for all 16 timesteps,
//       build cur0 (frame 0 + walls), copy frame 0 (3ch) to d_out.
// ---------------------------------------------------------------------------
__global__ __launch_bounds__(256) void prep_kernel(
    const float* __restrict__ x, const float* __restrict__ rec,
    const float* __restrict__ walls,
    float4* __restrict__ rec4, float4* __restrict__ cur0,
    float* __restrict__ dout)
{
    int id = blockIdx.x * 256 + threadIdx.x;
    if (id < 16 * HW) {
        int t = id / HW, p = id % HW;
        rec4[id] = make_float4(rec[(t * 3 + 0) * HW + p],
                               rec[(t * 3 + 1) * HW + p],
                               rec[(t * 3 + 2) * HW + p],
                               walls[p]);
    }
    if (id < HW) {
        cur0[id] = make_float4(x[0 * HW + id], x[1 * HW + id], x[2 * HW + id],
                               walls[id]);
    }
    if (id < 3 * HW) {
        dout[id] = x[id];  // frame 0, channels 0..2
    }
}

// ---------------------------------------------------------------------------
// dist: block = (t, sy), 720 blocks x 576 threads.
// Phase A (row ownership, 4 consecutive px/thread): F = 4ch sq-diff vs rec
//   shifted by (sy,sx), written to x-haloed FsP row.
// Phase B: row box-sums via 2x ds_read_b128 -> 4 R values, b128 write.
// Phase C (column ownership, 4 consecutive py/thread): col box-sums via 8
//   stride-1 b32 reads; packed (dist_bits<<32|idx) min into registers.
// Summation order identical to the round-1 kernel (bit-exact distances).
// Final: device-scope atomicMin into global best[2304].
// ---------------------------------------------------------------------------
__global__ __launch_bounds__(576) void dist_kernel(
    const float4* __restrict__ rec4, const float4* __restrict__ cur4,
    unsigned long long* __restrict__ best)
{
    __shared__ float4 recS[W48 * PAD_REC];   // 37632 B
    __shared__ float  FsP[W48 * FS_STRIDE];  // 10752 B
    __shared__ float  Rs[W48 * RS_STRIDE];   //  9984 B

    const int tid = threadIdx.x;             // 0..575
    const int b   = blockIdx.x;
    const int sy  = b % W48;
    const int t   = b / W48;

    // row ownership (phases A,B): yA = tid/12, x0A = 4*(tid%12)
    const int yA  = tid / 12;
    const int x0A = 4 * (tid % 12);
    int ryA = yA + sy; if (ryA >= W48) ryA -= W48;

    // column ownership (phase C): xC = tid%48, y0C = 4*(tid/48)
    const int xC  = tid % W48;
    const int y0C = 4 * (tid / W48);

    float4 curR[4];
#pragma unroll
    for (int i = 0; i < 4; i++) curR[i] = cur4[4 * tid + i];

    // stage rec[t] into padded LDS (coalesced: thread reads 64B contiguous)
#pragma unroll
    for (int i = 0; i < 4; i++)
        recS[yA * PAD_REC + x0A + i] = rec4[t * HW + 4 * tid + i];

    unsigned long long bst[4] = {~0ULL, ~0ULL, ~0ULL, ~0ULL};

    // phase-C wrapped row indices (y0C-2 .. y0C+5) and candidate rows
    int cyy[8];
#pragma unroll
    for (int j = 0; j < 8; j++) {
        int yy = y0C + j - 2;
        if (yy < 0) yy += W48;
        if (yy >= W48) yy -= W48;
        cyy[j] = yy;
    }
    int ryC[4];
#pragma unroll
    for (int i = 0; i < 4; i++) {
        int ry = y0C + i + sy; if (ry >= W48) ry -= W48;
        ryC[i] = ry;
    }

    __syncthreads();  // recS ready

    for (int sx = 0; sx < W48; sx++) {
        // ---- phase A: per-pixel 4ch squared diff ----
        float F[4];
        int rxb = x0A + sx; if (rxb >= W48) rxb -= W48;
#pragma unroll
        for (int i = 0; i < 4; i++) {
            int rx = rxb + i; if (rx >= W48) rx -= W48;
            float4 r = recS[ryA * PAD_REC + rx];
            float d0 = curR[i].x - r.x;
            float d1 = curR[i].y - r.y;
            float d2 = curR[i].z - r.z;
            float d3 = curR[i].w - r.w;
            F[i] = d0 * d0 + d1 * d1 + d2 * d2 + d3 * d3;
        }
        {
            float2* fw = (float2*)&FsP[yA * FS_STRIDE + 2 + x0A];
            fw[0] = make_float2(F[0], F[1]);
            fw[1] = make_float2(F[2], F[3]);
            // circular halo: FsP[i]=F[(i-2) mod 48], i in 0..51
            if (x0A == 0)
                *(float2*)&FsP[yA * FS_STRIDE + 50] = make_float2(F[0], F[1]);
            if (x0A == 44)
                *(float2*)&FsP[yA * FS_STRIDE + 0]  = make_float2(F[2], F[3]);
        }
        __syncthreads();

        // ---- phase B: row box-sums (order = F[x-2]+F[x-1]+F[x]+F[x+1]+F[x+2]) ----
        {
            float4 fa = *(const float4*)&FsP[yA * FS_STRIDE + x0A];
            float4 fb = *(const float4*)&FsP[yA * FS_STRIDE + x0A + 4];
            float R0 = fa.x + fa.y + fa.z + fa.w + fb.x;
            float R1 = fa.y + fa.z + fa.w + fb.x + fb.y;
            float R2 = fa.z + fa.w + fb.x + fb.y + fb.z;
            float R3 = fa.w + fb.x + fb.y + fb.z + fb.w;
            *(float4*)&Rs[yA * RS_STRIDE + x0A] = make_float4(R0, R1, R2, R3);
        }
        __syncthreads();

        // ---- phase C: column box-sums + packed-min (column ownership) ----
        {
            float rv[8];
#pragma unroll
            for (int j = 0; j < 8; j++) rv[j] = Rs[cyy[j] * RS_STRIDE + xC];
            int rx = xC + sx; if (rx >= W48) rx -= W48;
#pragma unroll
            for (int i = 0; i < 4; i++) {
                float d = rv[i] + rv[i + 1] + rv[i + 2] + rv[i + 3] + rv[i + 4];
                unsigned int m = (unsigned int)(t * HW + ryC[i] * W48 + rx);
                unsigned long long pk =
                    ((unsigned long long)__float_as_uint(d) << 32) | m;
                bst[i] = pk < bst[i] ? pk : bst[i];
            }
        }
        // no barrier needed: next-A writes FsP (last read in B, fenced by the
        // post-B barrier); next-B writes Rs (last read here, fenced by post-A).
    }

#pragma unroll
    for (int i = 0; i < 4; i++)
        atomicMin(&best[(y0C + i) * W48 + xC], bst[i]);
}

// ---------------------------------------------------------------------------
// gather: decode best[p]; gather center pixel of (t+1) patch; write output
// frame + next carry + per-element sq-error.
// ---------------------------------------------------------------------------
__global__ __launch_bounds__(256) void gather_kernel(
    const unsigned long long* __restrict__ best,
    const float4* __restrict__ rec4, const float* __restrict__ x,
    const float* __restrict__ walls,
    float4* __restrict__ curnext, float* __restrict__ dout,
    float* __restrict__ err, int step)
{
    int p = blockIdx.x * 256 + threadIdx.x;
    if (p >= HW) return;
    unsigned int m = (unsigned int)best[p];
    int t = m / HW, q = m % HW;
    float4 v = rec4[(t + 1) * HW + q];
    curnext[p] = v;
    dout[(step + 1) * 3 * HW + 0 * HW + p] = v.x;
    dout[(step + 1) * 3 * HW + 1 * HW + p] = v.y;
    dout[(step + 1) * 3 * HW + 2 * HW + p] = v.z;
    float t0 = x[((step + 1) * 3 + 0) * HW + p];
    float t1 = x[((step + 1) * 3 + 1) * HW + p];
    float t2 = x[((step + 1) * 3 + 2) * HW + p];
    float t3 = walls[p];
    float e = (v.x - t0) * (v.x - t0) + (v.y - t1) * (v.y - t1) +
              (v.z - t2) * (v.z - t2) + (v.w - t3) * (v.w - t3);
    err[step * HW + p] = e;
}

// ---------------------------------------------------------------------------
// loss: deterministic reduction; loss = total / 18432.
// ---------------------------------------------------------------------------
__global__ __launch_bounds__(256) void loss_kernel(
    const float* __restrict__ err, float* __restrict__ dout)
{
    __shared__ float ssum[256];
    float s = 0.f;
    for (int i = threadIdx.x; i < 2 * HW; i += 256) s += err[i];
    ssum[threadIdx.x] = s;
    __syncthreads();
    for (int w = 128; w > 0; w >>= 1) {
        if (threadIdx.x < w) ssum[threadIdx.x] += ssum[threadIdx.x + w];
        __syncthreads();
    }
    if (threadIdx.x == 0) dout[9 * HW] = ssum[0] / 18432.0f;
}

extern "C" void kernel_launch(void* const* d_in, const int* in_sizes, int n_in,
                              void* d_out, int out_size, void* d_ws,
                              size_t ws_size, hipStream_t stream)
{
    const float* x     = (const float*)d_in[0];
    const float* rec   = (const float*)d_in[1];
    const float* walls = (const float*)d_in[2];
    float* dout = (float*)d_out;

    char* ws = (char*)d_ws;
    float4* rec4 = (float4*)ws;                               // 589824 B
    float4* curb = (float4*)(ws + 589824);                    // 110592 B
    float*  err  = (float*)(ws + 589824 + 110592);            //  18432 B
    unsigned long long* best =
        (unsigned long long*)(ws + 589824 + 110592 + 18432);  //  18432 B

    prep_kernel<<<144, 256, 0, stream>>>(x, rec, walls, rec4, curb, dout);
    for (int step = 0; step < 2; step++) {
        hipMemsetAsync(best, 0xFF, (size_t)HW * 8, stream);
        dist_kernel<<<15 * W48, 576, 0, stream>>>(rec4, curb + step * HW, best);
        gather_kernel<<<9, 256, 0, stream>>>(best, rec4, x, walls,
                                             curb + (step + 1) * HW, dout, err,
                                             step);
    }
    loss_kernel<<<1, 256, 0, stream>>>(err, dout);
}